// Round 5
// baseline (1613.760 us; speedup 1.0000x reference)
//
#include <hip/hip_runtime.h>
#include <math.h>

#define TPB  128     // main/rescue
#define RTPB 256     // refine
#define EPS_GAP 1e-4f

typedef unsigned int u32;
typedef unsigned long long u64;

// ============ analytic fp32 scan: O(8) instead of O(240) ======================
// argmin d2 == argmax 2*dot(root,x). Pair family best = top-2 |x| w/ signs;
// half family best = sign pattern (parity-fixed at min |x|). Runner-up for the
// near-tie flag: pair = t1+t3; half = flip-two-smallest / flip-second-smallest.
__device__ __forceinline__ int scan_fast(const float* x, float scale,
                                         float* residual, bool protect, bool& flag){
    float aa[8]; int neg=0; float S=0.f;
    #pragma unroll
    for (int k=0;k<8;k++){
        float v=x[k]; float av=fabsf(v);
        aa[k]=av; S+=av; neg |= (v<0.f)?(1<<k):0;
    }
    float t1=-1e30f,t2=-1e30f,t3=-1e30f; int p1=0,p2=0;
    #pragma unroll
    for (int k=0;k<8;k++){
        float v=aa[k];
        bool g1=v>t1, g2=v>t2, g3=v>t3;
        t3 = g2 ? t2 : (g3 ? v : t3);
        t2 = g1 ? t1 : (g2 ? v : t2);
        p2 = g1 ? p1 : (g2 ? k : p2);
        t1 = g1 ? v : t1;
        p1 = g1 ? k : p1;
    }
    float n1=1e30f,n2v=1e30f; int m1=0;
    #pragma unroll
    for (int k=0;k<8;k++){
        float v=aa[k];
        bool l1=v<n1, l2=v<n2v;
        n2v = l1 ? n1 : (l2 ? v : n2v);
        n1  = l1 ? v : n1;
        m1  = l1 ? k : m1;
    }
    int bi = min(p1,p2), bj = max(p1,p2);
    float pv = 2.f*(t1+t2), pr = 2.f*(t1+t3);
    int par = __builtin_popcount((unsigned)neg)&1;
    float hv, hr; int hb;
    if (par==0){ hv=S;          hb=neg;           hr=S-2.f*(n1+n2v); }
    else       { hv=S-2.f*n1;   hb=neg^(1<<m1);   hr=S-2.f*n2v; }
    bool pair = (pv >= hv);                 // tie -> pair (lower index), np-compatible
    float best = pair? pv: hv, alt = pair? hv: pv;
    float second = fmaxf(alt, fmaxf(pr,hr));
    if (protect) flag = flag || ((best-second) < EPS_GAP);
    int s = (((neg>>bi)&1)<<1) | ((neg>>bj)&1);
    int pidx = 4*(7*bi - ((bi*(bi-1))>>1) + (bj-bi-1)) + s;
    int hidx = 112 + (hb>>1);
    float sI = ((neg>>bi)&1)? scale : -scale;     // residual -= coef*scale
    float sJ = ((neg>>bj)&1)? scale : -scale;
    #pragma unroll
    for (int k=0;k<8;k++){
        float cp = ((k==bi)? sI:0.f) + ((k==bj)? sJ:0.f);
        float ch = ((hb>>k)&1)? 0.5f*scale : -0.5f*scale;
        residual[k] += (pair? cp : ch);
    }
    return pair? pidx : hidx;
}

// ============ analytic f64 scan (rescue): same selection, exact precision =====
__device__ __forceinline__ int scan_fast_f64(const double* x, double scale,
                                             double* residual){
    double aa[8]; int neg=0; double S=0.0;
    #pragma unroll
    for (int k=0;k<8;k++){
        double v=x[k]; double av=fabs(v);
        aa[k]=av; S+=av; neg |= (v<0.0)?(1<<k):0;
    }
    double t1=-1e300,t2=-1e300; int p1=0,p2=0;
    #pragma unroll
    for (int k=0;k<8;k++){
        double v=aa[k];
        bool g1=v>t1, g2=v>t2;
        t2 = g1 ? t1 : (g2 ? v : t2);
        p2 = g1 ? p1 : (g2 ? k : p2);
        t1 = g1 ? v : t1;
        p1 = g1 ? k : p1;
    }
    double n1=1e300; int m1=0;
    #pragma unroll
    for (int k=0;k<8;k++){
        double v=aa[k];
        bool l1=v<n1;
        n1 = l1 ? v : n1;
        m1 = l1 ? k : m1;
    }
    int bi = min(p1,p2), bj = max(p1,p2);
    double pv = 2.0*(t1+t2);
    int par = __builtin_popcount((unsigned)neg)&1;
    double hv; int hb;
    if (par==0){ hv=S;          hb=neg; }
    else       { hv=S-2.0*n1;   hb=neg^(1<<m1); }
    bool pair = (pv >= hv);
    int s = (((neg>>bi)&1)<<1) | ((neg>>bj)&1);
    int pidx = 4*(7*bi - ((bi*(bi-1))>>1) + (bj-bi-1)) + s;
    int hidx = 112 + (hb>>1);
    double sI = ((neg>>bi)&1)? scale : -scale;
    double sJ = ((neg>>bj)&1)? scale : -scale;
    #pragma unroll
    for (int k=0;k<8;k++){
        double cp = ((k==bi)? sI:0.0) + ((k==bj)? sJ:0.0);
        double ch = ((hb>>k)&1)? 0.5*scale : -0.5*scale;
        residual[k] += (pair? cp : ch);
    }
    return pair? pidx : hidx;
}

// ============ phase B: softmax over 240 roots + hard gathers (pre-refine) =====
// T = per-thread LDS region (25 slots): [0..7]=q, [8..23]=lo16.
// zv is an opaque 0 living in a VGPR: adding it to table addresses forces the
// compiler to emit broadcast global_load_dwordx4 (deep vmcnt pipeline) instead
// of latency-serialized s_load for the 54 KB/row of uniform table reads.
__device__ __forceinline__ void phaseB(float* T, const float* qf,
    int i1,int i2,int i3,int i4,int i5,int i6,int i7, float decay, int zv,
    const float* __restrict__ lemb, const float* __restrict__ bcp,
    const float* __restrict__ rcpar, const float* __restrict__ bcx,
    float* __restrict__ orow)
{
    const float IS2 = 0.70710678118654752f;
    const float HS2 = 0.35355339059327376f;
    const float LG2 = 0.69314718055994531f;
    float hi16[16];
    {
        float a01p=qf[0]+qf[1], a01m=qf[0]-qf[1];
        float a23p=qf[2]+qf[3], a23m=qf[2]-qf[3];
        float a45p=qf[4]+qf[5], a45m=qf[4]-qf[5];
        float a67p=qf[6]+qf[7], a67m=qf[6]-qf[7];
        float s01[4]={a01p,-a01m,a01m,-a01p};
        float s23[4]={a23p,-a23m,a23m,-a23p};
        float s45[4]={a45p,-a45m,a45m,-a45p};
        float s67[4]={a67p,-a67m,a67m,-a67p};
        #pragma unroll
        for (int p=0;p<16;p++){ T[8+p]=s01[p&3]+s23[(p>>2)&3]; hi16[p]=s45[p&3]+s67[(p>>2)&3]; }
        #pragma unroll
        for (int k=0;k<8;k++) T[k]=qf[k];
    }
    float emb[52], ctl[4], den=0.f;
    #pragma unroll
    for (int k=0;k<52;k++) emb[k]=0.f;
    ctl[0]=ctl[1]=ctl[2]=ctl[3]=0.f;

    auto proc = [&](float sims, int j){
        float e = __expf(sims - bcx[j]*LG2);   // logits bounded by sqrt2; safe
        den += e;
        const float4* ep4 = (const float4*)(lemb + (size_t)j*52) + zv;  // VMEM broadcast
        #pragma unroll
        for (int t=0;t<13;t++){
            float4 v = ep4[t];
            emb[4*t+0]=fmaf(e,v.x,emb[4*t+0]); emb[4*t+1]=fmaf(e,v.y,emb[4*t+1]);
            emb[4*t+2]=fmaf(e,v.z,emb[4*t+2]); emb[4*t+3]=fmaf(e,v.w,emb[4*t+3]);
        }
        float4 cv = *((const float4*)(bcp + (size_t)j*4) + zv);
        ctl[0]=fmaf(e,cv.x,ctl[0]); ctl[1]=fmaf(e,cv.y,ctl[1]);
        ctl[2]=fmaf(e,cv.z,ctl[2]); ctl[3]=fmaf(e,cv.w,ctl[3]);
    };
    #pragma unroll
    for (int h=0;h<16;h++){                    // half roots: hi16 const-indexed
        float hv = hi16[h];
        int ph = __builtin_popcount(h)&1;
        for (int m=0;m<8;m++){
            int lo = (m<<1) | ((__builtin_popcount(m)&1)^ph);
            proc((T[8+lo]+hv)*HS2, 112 + (h<<3) + m);
        }
    }
    {
        int ii=0, jn=1;
        for (int pc=0;pc<28;++pc){             // pair roots via LDS q
            float a=T[ii], b=T[jn];
            float p=a+b, mm=a-b;
            proc( p*IS2, 4*pc+0);
            proc( mm*IS2,4*pc+1);
            proc(-mm*IS2,4*pc+2);
            proc(-p*IS2, 4*pc+3);
            if (++jn==8){ ++ii; jn=ii+1; }
        }
    }
    float rden = 1.f/den;
    #pragma unroll
    for (int k=0;k<52;k++) emb[k] *= rden;
    #pragma unroll
    for (int k=0;k<4;k++) ctl[k] *= rden;

    // hard-index gathers (per-lane float4, L2-resident tables)
    {
        float dp = decay;
        #define DO_G(LVL, IV) { \
            float ild = 1.0f/dp; \
            const float4* ep4 = (const float4*)(lemb + ((size_t)(LVL)*240 + (size_t)(IV))*52); \
            _Pragma("unroll") for (int t4=0;t4<13;t4++){ float4 v=ep4[t4]; \
                emb[4*t4+0]=fmaf(ild,v.x,emb[4*t4+0]); emb[4*t4+1]=fmaf(ild,v.y,emb[4*t4+1]); \
                emb[4*t4+2]=fmaf(ild,v.z,emb[4*t4+2]); emb[4*t4+3]=fmaf(ild,v.w,emb[4*t4+3]); } \
            float4 cv = *(const float4*)(rcpar + ((size_t)((LVL)-1)*240 + (size_t)(IV))*4); \
            ctl[0]=fmaf(ild,cv.x,ctl[0]); ctl[1]=fmaf(ild,cv.y,ctl[1]); \
            ctl[2]=fmaf(ild,cv.z,ctl[2]); ctl[3]=fmaf(ild,cv.w,ctl[3]); \
            dp *= decay; }
        DO_G(1,i1) DO_G(2,i2) DO_G(3,i3) DO_G(4,i4) DO_G(5,i5) DO_G(6,i6) DO_G(7,i7)
        #undef DO_G
    }
    float4* o4 = (float4*)orow;                // pre-refine output
    #pragma unroll
    for (int t=0;t<13;t++)
        o4[t] = make_float4(emb[4*t], emb[4*t+1], emb[4*t+2], emb[4*t+3]);
    o4[13] = make_float4(ctl[0], ctl[1], ctl[2], ctl[3]);
}

// ============ K1: fp32 A+B, flags near-ties, compacts rescue list =============
__global__ __launch_bounds__(TPB) void e8_main(
    const float* __restrict__ g_obs,
    const float* __restrict__ pw1, const float* __restrict__ pb1,
    const float* __restrict__ pw2, const float* __restrict__ pb2,
    const float* __restrict__ lemb, const float* __restrict__ bcp,
    const float* __restrict__ rcpar, const float* __restrict__ bcx,
    const float* __restrict__ glogdecay,
    u32* __restrict__ cnt, u32* __restrict__ list,
    unsigned char* __restrict__ flags, int useCompact,
    const int* __restrict__ zbuf,
    float* __restrict__ out, int B)
{
    __shared__ float smem[TPB*25];
    const int tid = threadIdx.x;
    const int row = blockIdx.x*TPB + tid;
    const int zv = zbuf[tid & 1];   // == 0, but in a VGPR and opaque to compiler

    {   // coalesced obs staging
        const size_t base = (size_t)blockIdx.x*TPB*14;
        const size_t lim  = (size_t)B*14;
        for (int t = tid; t < TPB*14; t += TPB){
            size_t g = base + (size_t)t;
            smem[t] = (g < lim) ? g_obs[g] : 0.f;
        }
    }
    __syncthreads();
    const bool active = row < B;

    float qf[8];
    int idxs[8] = {0,0,0,0,0,0,0,0};
    float decay = 1.f;
    bool flag = false;

    if (active){
        float ob[14];
        #pragma unroll
        for (int j=0;j<14;j++) ob[j]=smem[tid*14+j];
        float qa[8];
        #pragma unroll
        for (int m=0;m<8;m++) qa[m]=pb2[m];
        #pragma unroll 1
        for (int k=0;k<32;k++){
            float a = pb1[k];
            #pragma unroll
            for (int j=0;j<14;j++) a = fmaf(pw1[k*14+j], ob[j], a);
            float h = 0.5f*a*(1.f+erff(a*0.70710678f));
            #pragma unroll
            for (int m=0;m<8;m++) qa[m] = fmaf(pw2[m*32+k], h, qa[m]);
        }
        float n2=0.f;
        #pragma unroll
        for (int m=0;m<8;m++) n2 = fmaf(qa[m],qa[m],n2);
        float nr = fmaxf(sqrtf(n2), 1e-12f);
        float sc = 1.41421356237309505f/nr;
        float residual[8];
        #pragma unroll
        for (int m=0;m<8;m++){ qf[m]=qa[m]*sc; residual[m]=qf[m]; }

        decay = expf(glogdecay[0]);
        float dpow = 1.f;
        #pragma unroll
        for (int lvl=0; lvl<8; ++lvl){
            float rs = 0.5f*dpow;
            float x[8];
            #pragma unroll
            for (int k=0;k<8;k++) x[k]=residual[k]*rs;
            idxs[lvl] = scan_fast(x, 2.f/dpow, residual, (lvl<3), flag);
            dpow *= decay;
        }
    }

    if (useCompact){
        u64 mask = __ballot(flag);
        if (mask){
            int lane = tid & 63;
            int leader = __builtin_ctzll(mask);
            u32 base = 0;
            if (lane == leader) base = atomicAdd(cnt, (u32)__builtin_popcountll(mask));
            base = __shfl(base, leader, 64);
            if (flag){
                u32 pos = (u32)__builtin_popcountll(mask & ((1ull<<lane)-1ull));
                list[base+pos] = (u32)row;
            }
        }
    } else if (active){
        flags[row] = flag ? 1 : 0;
    }

    __syncthreads();   // obs region reused as per-thread tables
    if (active)
        phaseB(smem + tid*25, qf, idxs[1],idxs[2],idxs[3],idxs[4],idxs[5],idxs[6],idxs[7],
               decay, zv, lemb, bcp, rcpar, bcx, out + (size_t)row*56);
}

// ============ K2: f64 rescue (analytic scan; dense list or flags fallback) ====
__global__ __launch_bounds__(TPB) void e8_rescue(
    const float* __restrict__ g_obs,
    const float* __restrict__ pw1, const float* __restrict__ pb1,
    const float* __restrict__ pw2, const float* __restrict__ pb2,
    const float* __restrict__ lemb, const float* __restrict__ bcp,
    const float* __restrict__ rcpar, const float* __restrict__ bcx,
    const float* __restrict__ glogdecay,
    const u32* __restrict__ cnt, const u32* __restrict__ list,
    const unsigned char* __restrict__ flags, int useCompact,
    const int* __restrict__ zbuf,
    float* __restrict__ out, int B)
{
    __shared__ float smem[TPB*25];
    const int tid = threadIdx.x;
    const int zv = zbuf[tid & 1];
    int row;
    if (useCompact){
        u32 c = *cnt;
        if ((u32)blockIdx.x*TPB >= c) return;
        int gid = blockIdx.x*TPB + tid;
        if (gid >= (int)c) return;
        row = (int)list[gid];
    } else {
        row = blockIdx.x*TPB + tid;
        bool f = (row < B) && (flags[row] != 0);
        if (__ballot(f) == 0ull) return;
        if (!f) return;
    }

    double ob[14];
    #pragma unroll
    for (int j=0;j<14;j++) ob[j] = (double)g_obs[(size_t)row*14+j];
    double qa[8];
    #pragma unroll
    for (int m=0;m<8;m++) qa[m] = (double)pb2[m];
    #pragma unroll 1
    for (int k=0;k<32;k++){
        double a = (double)pb1[k];
        #pragma unroll
        for (int j=0;j<14;j++) a += (double)pw1[k*14+j]*ob[j];
        double hk = 0.5*a*(1.0 + erf(a*0.70710678118654752440));
        #pragma unroll
        for (int m=0;m<8;m++) qa[m] += (double)pw2[m*32+k]*hk;
    }
    double n2 = 0.0;
    #pragma unroll
    for (int m=0;m<8;m++) n2 += qa[m]*qa[m];
    double nr = sqrt(n2); if (nr < 1e-12) nr = 1e-12;
    double q[8], residual[8];
    #pragma unroll
    for (int m=0;m<8;m++){ q[m] = qa[m]/nr*1.4142135623730951; residual[m]=q[m]; }

    double decay_d = exp((double)glogdecay[0]);
    double dpow = 1.0;
    int idxs[8] = {0,0,0,0,0,0,0,0};
    #pragma unroll
    for (int lvl=0; lvl<8; ++lvl){
        double rs = 0.5*dpow;
        double x[8];
        #pragma unroll
        for (int k=0;k<8;k++) x[k]=residual[k]*rs;
        idxs[lvl] = scan_fast_f64(x, 2.0/dpow, residual);
        dpow *= decay_d;
    }
    float qf[8];
    #pragma unroll
    for (int m=0;m<8;m++) qf[m]=(float)q[m];
    phaseB(smem + tid*25, qf, idxs[1],idxs[2],idxs[3],idxs[4],idxs[5],idxs[6],idxs[7],
           (float)decay_d, zv, lemb, bcp, rcpar, bcx, out + (size_t)row*56);
}

// ============ K3: gated refinement MLP, RMW on out (emb part only) ============
// out_emb = (emb + sg*b2) + sum_k (sg*gelu_k) * W2[:,k]
__global__ __launch_bounds__(RTPB) void e8_refine(
    const float* __restrict__ rw1, const float* __restrict__ rb1,
    const float* __restrict__ rw2, const float* __restrict__ rb2,
    const float* __restrict__ rgate, const int* __restrict__ zbuf,
    float* __restrict__ out, int B)
{
    const int tid = threadIdx.x;
    const int row = blockIdx.x*RTPB + tid;
    if (row >= B) return;
    const int zv = zbuf[tid & 1];
    float* orow = out + (size_t)row*56;
    float emb[52];
    {
        const float4* o4 = (const float4*)orow;
        #pragma unroll
        for (int t=0;t<13;t++){
            float4 v = o4[t];
            emb[4*t]=v.x; emb[4*t+1]=v.y; emb[4*t+2]=v.z; emb[4*t+3]=v.w;
        }
    }
    float sg = 1.f/(1.f+__expf(-rgate[0]));
    float g[52];
    #pragma unroll
    for (int k=0;k<52;k++){                      // pass 1 (emb pristine)
        const float4* w4 = (const float4*)(rw1 + (size_t)k*52) + zv;   // VMEM broadcast
        float a0=0.f,a1=0.f,a2=0.f,a3=0.f;
        #pragma unroll
        for (int t=0;t<13;t++){
            float4 w = w4[t];
            a0=fmaf(w.x,emb[4*t+0],a0); a1=fmaf(w.y,emb[4*t+1],a1);
            a2=fmaf(w.z,emb[4*t+2],a2); a3=fmaf(w.w,emb[4*t+3],a3);
        }
        float a = ((a0+a1)+(a2+a3)) + rb1[k];
        g[k] = sg*0.5f*a*(1.f+erff(a*0.70710678f));
    }
    #pragma unroll
    for (int m=0;m<52;m++) emb[m] = fmaf(sg, rb2[m], emb[m]);
    #pragma unroll
    for (int m=0;m<52;m++){                      // pass 2: W2 row-contiguous
        const float4* w4 = (const float4*)(rw2 + (size_t)m*52) + zv;
        float a0=0.f,a1=0.f,a2=0.f,a3=0.f;
        #pragma unroll
        for (int t=0;t<13;t++){
            float4 w = w4[t];
            a0=fmaf(w.x,g[4*t+0],a0); a1=fmaf(w.y,g[4*t+1],a1);
            a2=fmaf(w.z,g[4*t+2],a2); a3=fmaf(w.w,g[4*t+3],a3);
        }
        emb[m] += ((a0+a1)+(a2+a3));
    }
    float4* o4 = (float4*)orow;
    #pragma unroll
    for (int t=0;t<13;t++)
        o4[t] = make_float4(emb[4*t], emb[4*t+1], emb[4*t+2], emb[4*t+3]);
    // ctl (o4[13]) untouched
}

extern "C" void kernel_launch(void* const* d_in, const int* in_sizes, int n_in,
                              void* d_out, int out_size, void* d_ws, size_t ws_size,
                              hipStream_t stream)
{
    const float* obs  = (const float*)d_in[0];
    const float* pw1  = (const float*)d_in[1];
    const float* pb1  = (const float*)d_in[2];
    const float* pw2  = (const float*)d_in[3];
    const float* pb2  = (const float*)d_in[4];
    const float* lemb = (const float*)d_in[5];
    const float* bcp  = (const float*)d_in[6];
    const float* rcp  = (const float*)d_in[7];
    const float* bcx  = (const float*)d_in[8];
    const float* ld   = (const float*)d_in[9];
    const float* rw1  = (const float*)d_in[10];
    const float* rb1  = (const float*)d_in[11];
    const float* rw2  = (const float*)d_in[12];
    const float* rb2  = (const float*)d_in[13];
    const float* rg   = (const float*)d_in[14];

    int B = in_sizes[0] / 14;
    int grid  = (B + TPB - 1) / TPB;
    int rgrid = (B + RTPB - 1) / RTPB;

    bool compact = ws_size >= (size_t)256 + (size_t)B*4;
    u32* cnt  = (u32*)d_ws;                      // offset 0
    const int* zbuf = (const int*)d_ws + 2;      // offsets 8..15: opaque zeros
    u32* list = (u32*)d_ws + 64;                 // offset 256
    unsigned char* flags = (unsigned char*)d_ws + 256; // fallback layout

    hipMemsetAsync(d_ws, 0, 16, stream);         // zero cnt + zbuf

    e8_main<<<grid, TPB, 0, stream>>>(obs, pw1, pb1, pw2, pb2, lemb, bcp, rcp, bcx, ld,
                                      cnt, list, flags, compact?1:0, zbuf,
                                      (float*)d_out, B);
    e8_rescue<<<grid, TPB, 0, stream>>>(obs, pw1, pb1, pw2, pb2, lemb, bcp, rcp, bcx, ld,
                                        cnt, list, flags, compact?1:0, zbuf,
                                        (float*)d_out, B);
    e8_refine<<<rgrid, RTPB, 0, stream>>>(rw1, rb1, rw2, rb2, rg, zbuf, (float*)d_out, B);
}

// Round 6
// 483.189 us; speedup vs baseline: 3.3398x; 3.3398x over previous
//
#include <hip/hip_runtime.h>
#include <math.h>

#define TPB  256     // main / refine
#define RTPB 128     // rescue
#define EPS_GAP 1e-4f
#define LTAB 13440   // 240*56 fused [lemb0|bcp] table (floats)
#define LDSZ 13680   // + 240 bcx

typedef unsigned int u32;
typedef unsigned long long u64;

// ============ analytic fp32 scan: O(8) per level =============================
// argmin d2 == argmax 2*dot(root,x). Pair family best = top-2 |x| w/ signs;
// half family best = sign pattern (parity-fixed at min |x|). Runner-up for the
// near-tie flag: pair = t1+t3; half = flip-two-smallest / flip-second-smallest.
__device__ __forceinline__ int scan_fast(const float* x, float scale,
                                         float* residual, bool protect, bool& flag){
    float aa[8]; int neg=0; float S=0.f;
    #pragma unroll
    for (int k=0;k<8;k++){
        float v=x[k]; float av=fabsf(v);
        aa[k]=av; S+=av; neg |= (v<0.f)?(1<<k):0;
    }
    float t1=-1e30f,t2=-1e30f,t3=-1e30f; int p1=0,p2=0;
    #pragma unroll
    for (int k=0;k<8;k++){
        float v=aa[k];
        bool g1=v>t1, g2=v>t2, g3=v>t3;
        t3 = g2 ? t2 : (g3 ? v : t3);
        t2 = g1 ? t1 : (g2 ? v : t2);
        p2 = g1 ? p1 : (g2 ? k : p2);
        t1 = g1 ? v : t1;
        p1 = g1 ? k : p1;
    }
    float n1=1e30f,n2v=1e30f; int m1=0;
    #pragma unroll
    for (int k=0;k<8;k++){
        float v=aa[k];
        bool l1=v<n1, l2=v<n2v;
        n2v = l1 ? n1 : (l2 ? v : n2v);
        n1  = l1 ? v : n1;
        m1  = l1 ? k : m1;
    }
    int bi = min(p1,p2), bj = max(p1,p2);
    float pv = 2.f*(t1+t2), pr = 2.f*(t1+t3);
    int par = __builtin_popcount((unsigned)neg)&1;
    float hv, hr; int hb;
    if (par==0){ hv=S;          hb=neg;           hr=S-2.f*(n1+n2v); }
    else       { hv=S-2.f*n1;   hb=neg^(1<<m1);   hr=S-2.f*n2v; }
    bool pair = (pv >= hv);                 // tie -> pair (lower index), np-compatible
    float best = pair? pv: hv, alt = pair? hv: pv;
    float second = fmaxf(alt, fmaxf(pr,hr));
    if (protect) flag = flag || ((best-second) < EPS_GAP);
    int s = (((neg>>bi)&1)<<1) | ((neg>>bj)&1);
    int pidx = 4*(7*bi - ((bi*(bi-1))>>1) + (bj-bi-1)) + s;
    int hidx = 112 + (hb>>1);
    float sI = ((neg>>bi)&1)? scale : -scale;     // residual -= coef*scale
    float sJ = ((neg>>bj)&1)? scale : -scale;
    #pragma unroll
    for (int k=0;k<8;k++){
        float cp = ((k==bi)? sI:0.f) + ((k==bj)? sJ:0.f);
        float ch = ((hb>>k)&1)? 0.5f*scale : -0.5f*scale;
        residual[k] += (pair? cp : ch);
    }
    return pair? pidx : hidx;
}

// ============ analytic f64 scan (rescue): same selection, exact precision =====
__device__ __forceinline__ int scan_fast_f64(const double* x, double scale,
                                             double* residual){
    double aa[8]; int neg=0; double S=0.0;
    #pragma unroll
    for (int k=0;k<8;k++){
        double v=x[k]; double av=fabs(v);
        aa[k]=av; S+=av; neg |= (v<0.0)?(1<<k):0;
    }
    double t1=-1e300,t2=-1e300; int p1=0,p2=0;
    #pragma unroll
    for (int k=0;k<8;k++){
        double v=aa[k];
        bool g1=v>t1, g2=v>t2;
        t2 = g1 ? t1 : (g2 ? v : t2);
        p2 = g1 ? p1 : (g2 ? k : p2);
        t1 = g1 ? v : t1;
        p1 = g1 ? k : p1;
    }
    double n1=1e300; int m1=0;
    #pragma unroll
    for (int k=0;k<8;k++){
        double v=aa[k];
        bool l1=v<n1;
        n1 = l1 ? v : n1;
        m1 = l1 ? k : m1;
    }
    int bi = min(p1,p2), bj = max(p1,p2);
    double pv = 2.0*(t1+t2);
    int par = __builtin_popcount((unsigned)neg)&1;
    double hv; int hb;
    if (par==0){ hv=S;          hb=neg; }
    else       { hv=S-2.0*n1;   hb=neg^(1<<m1); }
    bool pair = (pv >= hv);
    int s = (((neg>>bi)&1)<<1) | ((neg>>bj)&1);
    int pidx = 4*(7*bi - ((bi*(bi-1))>>1) + (bj-bi-1)) + s;
    int hidx = 112 + (hb>>1);
    double sI = ((neg>>bi)&1)? scale : -scale;
    double sJ = ((neg>>bj)&1)? scale : -scale;
    #pragma unroll
    for (int k=0;k<8;k++){
        double cp = ((k==bi)? sI:0.0) + ((k==bj)? sJ:0.0);
        double ch = ((hb>>k)&1)? 0.5*scale : -0.5*scale;
        residual[k] += (pair? cp : ch);
    }
    return pair? pidx : hidx;
}

// ============ phase B: softmax over 240 roots + hard gathers (pre-refine) =====
// L = block-shared fused table: [j*56+c] = lemb0[j][c] (c<52) | bcp[j][c-52];
// L[LTAB+j] = bcx[j]. All wave-uniform reads -> ds_read broadcasts (no sK$
// thrash, no VGPR pressure). T = per-thread LDS region (25-stride):
// [0..7]=q, [8..23]=lo16 (runtime-indexed sims tables).
__device__ __forceinline__ void phaseB(const float* __restrict__ L, float* T,
    const float* qf,
    int i1,int i2,int i3,int i4,int i5,int i6,int i7, float decay,
    const float* __restrict__ lemb, const float* __restrict__ rcpar,
    float* __restrict__ orow)
{
    const float IS2 = 0.70710678118654752f;
    const float HS2 = 0.35355339059327376f;
    const float LG2 = 0.69314718055994531f;
    float hi16[16];
    {
        float a01p=qf[0]+qf[1], a01m=qf[0]-qf[1];
        float a23p=qf[2]+qf[3], a23m=qf[2]-qf[3];
        float a45p=qf[4]+qf[5], a45m=qf[4]-qf[5];
        float a67p=qf[6]+qf[7], a67m=qf[6]-qf[7];
        float s01[4]={a01p,-a01m,a01m,-a01p};
        float s23[4]={a23p,-a23m,a23m,-a23p};
        float s45[4]={a45p,-a45m,a45m,-a45p};
        float s67[4]={a67p,-a67m,a67m,-a67p};
        #pragma unroll
        for (int p=0;p<16;p++){ T[8+p]=s01[p&3]+s23[(p>>2)&3]; hi16[p]=s45[p&3]+s67[(p>>2)&3]; }
        #pragma unroll
        for (int k=0;k<8;k++) T[k]=qf[k];
    }
    float emb[56], den=0.f;     // [0..51]=embedding, [52..55]=control
    #pragma unroll
    for (int k=0;k<56;k++) emb[k]=0.f;

    auto proc = [&](float sims, int j){
        float e = __expf(sims - L[LTAB + j]*LG2);   // logits bounded by sqrt2
        den += e;
        const float4* Lr = (const float4*)(L + j*56);   // ds_read_b128 broadcast
        #pragma unroll
        for (int t=0;t<14;t++){
            float4 v = Lr[t];
            emb[4*t+0]=fmaf(e,v.x,emb[4*t+0]); emb[4*t+1]=fmaf(e,v.y,emb[4*t+1]);
            emb[4*t+2]=fmaf(e,v.z,emb[4*t+2]); emb[4*t+3]=fmaf(e,v.w,emb[4*t+3]);
        }
    };
    #pragma unroll
    for (int h=0;h<16;h++){                    // half roots: hi16 const-indexed
        float hv = hi16[h];
        int ph = __builtin_popcount(h)&1;
        #pragma unroll 1
        for (int m=0;m<8;m++){
            int lo = (m<<1) | ((__builtin_popcount(m)&1)^ph);
            proc((T[8+lo]+hv)*HS2, 112 + (h<<3) + m);
        }
    }
    {
        int ii=0, jn=1;
        #pragma unroll 1
        for (int pc=0;pc<28;++pc){             // pair roots via per-thread LDS q
            float a=T[ii], b=T[jn];
            float p=a+b, mm=a-b;
            proc( p*IS2, 4*pc+0);
            proc( mm*IS2,4*pc+1);
            proc(-mm*IS2,4*pc+2);
            proc(-p*IS2, 4*pc+3);
            if (++jn==8){ ++ii; jn=ii+1; }
        }
    }
    float rden = 1.f/den;
    #pragma unroll
    for (int k=0;k<56;k++) emb[k] *= rden;

    // hard-index gathers (per-lane float4, L2-resident tables)
    {
        float dp = decay;
        #define DO_G(LVL, IV) { \
            float ild = 1.0f/dp; \
            const float4* ep4 = (const float4*)(lemb + ((size_t)(LVL)*240 + (size_t)(IV))*52); \
            _Pragma("unroll") for (int t4=0;t4<13;t4++){ float4 v=ep4[t4]; \
                emb[4*t4+0]=fmaf(ild,v.x,emb[4*t4+0]); emb[4*t4+1]=fmaf(ild,v.y,emb[4*t4+1]); \
                emb[4*t4+2]=fmaf(ild,v.z,emb[4*t4+2]); emb[4*t4+3]=fmaf(ild,v.w,emb[4*t4+3]); } \
            float4 cv = *(const float4*)(rcpar + ((size_t)((LVL)-1)*240 + (size_t)(IV))*4); \
            emb[52]=fmaf(ild,cv.x,emb[52]); emb[53]=fmaf(ild,cv.y,emb[53]); \
            emb[54]=fmaf(ild,cv.z,emb[54]); emb[55]=fmaf(ild,cv.w,emb[55]); \
            dp *= decay; }
        DO_G(1,i1) DO_G(2,i2) DO_G(3,i3) DO_G(4,i4) DO_G(5,i5) DO_G(6,i6) DO_G(7,i7)
        #undef DO_G
    }
    float4* o4 = (float4*)orow;                // pre-refine output
    #pragma unroll
    for (int t=0;t<14;t++)
        o4[t] = make_float4(emb[4*t], emb[4*t+1], emb[4*t+2], emb[4*t+3]);
}

// staging helper: fused level-0 table into LDS
__device__ __forceinline__ void stageL(float* L, int tid, int tpb,
    const float* __restrict__ lemb, const float* __restrict__ bcp,
    const float* __restrict__ bcx)
{
    for (int t = tid; t < LTAB; t += tpb){
        int j = t/56, c = t - j*56;
        L[t] = (c < 52) ? lemb[j*52 + c] : bcp[j*4 + (c-52)];
    }
    for (int t = tid; t < 240; t += tpb) L[LTAB + t] = bcx[t];
}

// ============ K1: fp32 A+B, flags near-ties, compacts rescue list =============
__global__ __launch_bounds__(TPB) void e8_main(
    const float* __restrict__ g_obs,
    const float* __restrict__ pw1, const float* __restrict__ pb1,
    const float* __restrict__ pw2, const float* __restrict__ pb2,
    const float* __restrict__ lemb, const float* __restrict__ bcp,
    const float* __restrict__ rcpar, const float* __restrict__ bcx,
    const float* __restrict__ glogdecay,
    u32* __restrict__ cnt, u32* __restrict__ list,
    unsigned char* __restrict__ flags, int useCompact,
    float* __restrict__ out, int B)
{
    __shared__ float L[LDSZ];          // 54.7 KB fused level-0 tables
    __shared__ float Ttab[TPB*25];     // 25.6 KB per-thread tables (stride 25: 2-way=free)
    const int tid = threadIdx.x;
    const int row = blockIdx.x*TPB + tid;

    stageL(L, tid, TPB, lemb, bcp, bcx);
    {   // coalesced obs staging into per-thread T slots 0..13
        const size_t base = (size_t)blockIdx.x*TPB*14;
        const size_t lim  = (size_t)B*14;
        for (int t = tid; t < TPB*14; t += TPB){
            size_t g = base + (size_t)t;
            float v = (g < lim) ? g_obs[g] : 0.f;
            int r = t/14, c = t - r*14;
            Ttab[r*25 + c] = v;
        }
    }
    __syncthreads();
    const bool active = row < B;
    float* T = Ttab + tid*25;

    float qf[8];
    int idxs[8] = {0,0,0,0,0,0,0,0};
    float decay = 1.f;
    bool flag = false;

    if (active){
        float ob[14];
        #pragma unroll
        for (int j=0;j<14;j++) ob[j]=T[j];
        float qa[8];
        #pragma unroll
        for (int m=0;m<8;m++) qa[m]=pb2[m];
        #pragma unroll 1
        for (int k=0;k<32;k++){
            float a = pb1[k];
            #pragma unroll
            for (int j=0;j<14;j++) a = fmaf(pw1[k*14+j], ob[j], a);
            float h = 0.5f*a*(1.f+erff(a*0.70710678f));
            #pragma unroll
            for (int m=0;m<8;m++) qa[m] = fmaf(pw2[m*32+k], h, qa[m]);
        }
        float n2=0.f;
        #pragma unroll
        for (int m=0;m<8;m++) n2 = fmaf(qa[m],qa[m],n2);
        float nr = fmaxf(sqrtf(n2), 1e-12f);
        float sc = 1.41421356237309505f/nr;
        float residual[8];
        #pragma unroll
        for (int m=0;m<8;m++){ qf[m]=qa[m]*sc; residual[m]=qf[m]; }

        decay = expf(glogdecay[0]);
        float dpow = 1.f;
        #pragma unroll
        for (int lvl=0; lvl<8; ++lvl){
            float rs = 0.5f*dpow;
            float x[8];
            #pragma unroll
            for (int k=0;k<8;k++) x[k]=residual[k]*rs;
            idxs[lvl] = scan_fast(x, 2.f/dpow, residual, (lvl<3), flag);
            dpow *= decay;
        }
    }

    if (useCompact){
        u64 mask = __ballot(flag);
        if (mask){
            int lane = tid & 63;
            int leader = __builtin_ctzll(mask);
            u32 base = 0;
            if (lane == leader) base = atomicAdd(cnt, (u32)__builtin_popcountll(mask));
            base = __shfl(base, leader, 64);
            if (flag){
                u32 pos = (u32)__builtin_popcountll(mask & ((1ull<<lane)-1ull));
                list[base+pos] = (u32)row;
            }
        }
    } else if (active){
        flags[row] = flag ? 1 : 0;
    }

    if (active)    // T's obs slots are overwritten by this thread only (no sync needed)
        phaseB(L, T, qf, idxs[1],idxs[2],idxs[3],idxs[4],idxs[5],idxs[6],idxs[7],
               decay, lemb, rcpar, out + (size_t)row*56);
}

// ============ K2: f64 rescue (analytic scan; dense list or flags fallback) ====
__global__ __launch_bounds__(RTPB) void e8_rescue(
    const float* __restrict__ g_obs,
    const float* __restrict__ pw1, const float* __restrict__ pb1,
    const float* __restrict__ pw2, const float* __restrict__ pb2,
    const float* __restrict__ lemb, const float* __restrict__ bcp,
    const float* __restrict__ rcpar, const float* __restrict__ bcx,
    const float* __restrict__ glogdecay,
    const u32* __restrict__ cnt, const u32* __restrict__ list,
    const unsigned char* __restrict__ flags, int useCompact,
    float* __restrict__ out, int B)
{
    __shared__ float L[LDSZ];
    __shared__ float Ttab[RTPB*25];
    const int tid = threadIdx.x;
    int row = -1;
    bool valid;
    if (useCompact){
        u32 c = *cnt;
        if ((u32)(blockIdx.x*RTPB) >= c) return;      // uniform early-out
        int gid = blockIdx.x*RTPB + tid;
        valid = (gid < (int)c);
        if (valid) row = (int)list[gid];
    } else {
        row = blockIdx.x*RTPB + tid;
        valid = (row < B) && (flags[row] != 0);
        if (!__syncthreads_or(valid ? 1 : 0)) return; // uniform early-out
    }
    stageL(L, tid, RTPB, lemb, bcp, bcx);
    __syncthreads();
    if (!valid) return;

    double ob[14];
    #pragma unroll
    for (int j=0;j<14;j++) ob[j] = (double)g_obs[(size_t)row*14+j];
    double qa[8];
    #pragma unroll
    for (int m=0;m<8;m++) qa[m] = (double)pb2[m];
    #pragma unroll 1
    for (int k=0;k<32;k++){
        double a = (double)pb1[k];
        #pragma unroll
        for (int j=0;j<14;j++) a += (double)pw1[k*14+j]*ob[j];
        double hk = 0.5*a*(1.0 + erf(a*0.70710678118654752440));
        #pragma unroll
        for (int m=0;m<8;m++) qa[m] += (double)pw2[m*32+k]*hk;
    }
    double n2 = 0.0;
    #pragma unroll
    for (int m=0;m<8;m++) n2 += qa[m]*qa[m];
    double nr = sqrt(n2); if (nr < 1e-12) nr = 1e-12;
    double q[8], residual[8];
    #pragma unroll
    for (int m=0;m<8;m++){ q[m] = qa[m]/nr*1.4142135623730951; residual[m]=q[m]; }

    double decay_d = exp((double)glogdecay[0]);
    double dpow = 1.0;
    int idxs[8] = {0,0,0,0,0,0,0,0};
    #pragma unroll
    for (int lvl=0; lvl<8; ++lvl){
        double rs = 0.5*dpow;
        double x[8];
        #pragma unroll
        for (int k=0;k<8;k++) x[k]=residual[k]*rs;
        idxs[lvl] = scan_fast_f64(x, 2.0/dpow, residual);
        dpow *= decay_d;
    }
    float qf[8];
    #pragma unroll
    for (int m=0;m<8;m++) qf[m]=(float)q[m];
    phaseB(L, Ttab + tid*25, qf, idxs[1],idxs[2],idxs[3],idxs[4],idxs[5],idxs[6],idxs[7],
           (float)decay_d, lemb, rcpar, out + (size_t)row*56);
}

// ============ K3: gated refinement MLP, RMW on out (emb part only) ============
// out_emb = emb + sg*b2 + sum_k (sg*gelu(W1[k]·emb + b1[k])) * W2T[k][:]
// Weights staged in LDS (W2 transposed at stage time) -> broadcast ds reads.
__global__ __launch_bounds__(TPB) void e8_refine(
    const float* __restrict__ rw1, const float* __restrict__ rb1,
    const float* __restrict__ rw2, const float* __restrict__ rb2,
    const float* __restrict__ rgate,
    float* __restrict__ out, int B)
{
    __shared__ float W1[2704];     // [k][j] row-major (as given)
    __shared__ float W2T[2704];    // [k][m] = rw2[m][k]
    __shared__ float Bv[104];      // [0..51]=rb1, [52..103]=rb2
    const int tid = threadIdx.x;
    for (int t = tid; t < 2704; t += TPB) W1[t] = rw1[t];
    for (int t = tid; t < 2704; t += TPB){
        int m = t/52, k = t - m*52;
        W2T[k*52 + m] = rw2[t];
    }
    for (int t = tid; t < 104; t += TPB) Bv[t] = (t < 52) ? rb1[t] : rb2[t-52];
    __syncthreads();

    const int row = blockIdx.x*TPB + tid;
    if (row >= B) return;
    float* orow = out + (size_t)row*56;
    float emb[52];
    {
        const float4* o4 = (const float4*)orow;
        #pragma unroll
        for (int t=0;t<13;t++){
            float4 v = o4[t];
            emb[4*t]=v.x; emb[4*t+1]=v.y; emb[4*t+2]=v.z; emb[4*t+3]=v.w;
        }
    }
    float sg = 1.f/(1.f+__expf(-rgate[0]));
    float acc[52];
    #pragma unroll
    for (int m=0;m<52;m++) acc[m]=0.f;
    #pragma unroll 1
    for (int k=0;k<52;k++){
        const float4* w1 = (const float4*)(W1 + k*52);    // broadcast
        float a0=0.f,a1=0.f,a2=0.f,a3=0.f;
        #pragma unroll
        for (int t=0;t<13;t++){
            float4 w = w1[t];
            a0=fmaf(w.x,emb[4*t+0],a0); a1=fmaf(w.y,emb[4*t+1],a1);
            a2=fmaf(w.z,emb[4*t+2],a2); a3=fmaf(w.w,emb[4*t+3],a3);
        }
        float a = ((a0+a1)+(a2+a3)) + Bv[k];
        float gk = sg*0.5f*a*(1.f+erff(a*0.70710678f));
        const float4* w2 = (const float4*)(W2T + k*52);   // broadcast
        #pragma unroll
        for (int t=0;t<13;t++){
            float4 w = w2[t];
            acc[4*t+0]=fmaf(gk,w.x,acc[4*t+0]); acc[4*t+1]=fmaf(gk,w.y,acc[4*t+1]);
            acc[4*t+2]=fmaf(gk,w.z,acc[4*t+2]); acc[4*t+3]=fmaf(gk,w.w,acc[4*t+3]);
        }
    }
    float4* o4 = (float4*)orow;
    #pragma unroll
    for (int t=0;t<13;t++){
        float4 v;
        v.x = emb[4*t+0] + fmaf(sg, Bv[52+4*t+0], acc[4*t+0]);
        v.y = emb[4*t+1] + fmaf(sg, Bv[52+4*t+1], acc[4*t+1]);
        v.z = emb[4*t+2] + fmaf(sg, Bv[52+4*t+2], acc[4*t+2]);
        v.w = emb[4*t+3] + fmaf(sg, Bv[52+4*t+3], acc[4*t+3]);
        o4[t] = v;
    }
    // ctl (o4[13]) untouched
}

extern "C" void kernel_launch(void* const* d_in, const int* in_sizes, int n_in,
                              void* d_out, int out_size, void* d_ws, size_t ws_size,
                              hipStream_t stream)
{
    const float* obs  = (const float*)d_in[0];
    const float* pw1  = (const float*)d_in[1];
    const float* pb1  = (const float*)d_in[2];
    const float* pw2  = (const float*)d_in[3];
    const float* pb2  = (const float*)d_in[4];
    const float* lemb = (const float*)d_in[5];
    const float* bcp  = (const float*)d_in[6];
    const float* rcp  = (const float*)d_in[7];
    const float* bcx  = (const float*)d_in[8];
    const float* ld   = (const float*)d_in[9];
    const float* rw1  = (const float*)d_in[10];
    const float* rb1  = (const float*)d_in[11];
    const float* rw2  = (const float*)d_in[12];
    const float* rb2  = (const float*)d_in[13];
    const float* rg   = (const float*)d_in[14];

    int B = in_sizes[0] / 14;
    int grid  = (B + TPB - 1) / TPB;
    int rgrid = (B + RTPB - 1) / RTPB;

    bool compact = ws_size >= (size_t)256 + (size_t)B*4;
    u32* cnt  = (u32*)d_ws;                      // offset 0
    u32* list = (u32*)d_ws + 64;                 // offset 256
    unsigned char* flags = (unsigned char*)d_ws + 256; // fallback layout

    hipMemsetAsync(d_ws, 0, 8, stream);          // zero rescue counter

    e8_main<<<grid, TPB, 0, stream>>>(obs, pw1, pb1, pw2, pb2, lemb, bcp, rcp, bcx, ld,
                                      cnt, list, flags, compact?1:0, (float*)d_out, B);
    e8_rescue<<<rgrid, RTPB, 0, stream>>>(obs, pw1, pb1, pw2, pb2, lemb, bcp, rcp, bcx, ld,
                                          cnt, list, flags, compact?1:0, (float*)d_out, B);
    e8_refine<<<grid, TPB, 0, stream>>>(rw1, rb1, rw2, rb2, rg, (float*)d_out, B);
}